// Round 1
// baseline (221.573 us; speedup 1.0000x reference)
//
#include <hip/hip_runtime.h>
#include <math.h>

#define N_ 32
#define D_ 512
#define S_ 1600
#define K_ 64
#define NSP 8    // agg partials per n (blocks per n)

#define TP 536   // T pitch (bf16 elems): 1072 B rows, 16B-aligned, 12-dword bank skew
#define AP 72    // a' pitch (bf16 elems): 144 B rows, 16B-aligned
#define PP 68    // pssq pitch (f32): 16B-aligned, 4-dword bank skew

typedef __attribute__((ext_vector_type(8))) short short8;   // 8 bf16 (A/B frag)
typedef __attribute__((ext_vector_type(4))) float f32x4;    // acc frag
typedef __attribute__((ext_vector_type(2))) unsigned u32x2; // 8-B LDS store

// float -> bf16 (round to nearest even), bit pattern in short
static __device__ __forceinline__ short f2bf(float f) {
    unsigned u = __float_as_uint(f);
    u += 0x7fffu + ((u >> 16) & 1u);
    return (short)(u >> 16);
}
// pack two floats into (bf16(a) | bf16(b)<<16)
static __device__ __forceinline__ unsigned pk2(float a, float b) {
    return (unsigned)(unsigned short)f2bf(a) | ((unsigned)(unsigned short)f2bf(b) << 16);
}

// ---------------------------------------------------------------------------
// kW: conv_weight [64][512] fp32 -> bf16
// ---------------------------------------------------------------------------
__global__ __launch_bounds__(256) void kW(const float* __restrict__ w,
                                          short* __restrict__ w16)
{
    int i4 = (blockIdx.x * 256 + threadIdx.x) * 4;   // 32 blocks: 32768 elems
    float4 v = *(const float4*)&w[i4];
    short4 h = {f2bf(v.x), f2bf(v.y), f2bf(v.z), f2bf(v.w)};
    *(short4*)&w16[i4] = h;
}

// ---------------------------------------------------------------------------
// kF: fused logits -> softmax -> agg. One block per (n, bj); bj in [0,8).
// Block = 512 thr (8 waves). Each block processes subtiles {bj + 8*it} (64 s
// each; bj==0 also takes subtile 24), staging x bf16-transposed in LDS once,
// computing logits via MFMA (w16 A-frags from L2), softmax over k in-block,
// relaying a' = p*inv through LDS, and accumulating agg[k][d] in AGPRs with
// x B-frags re-read from L2 (same addresses just staged). Writes one fp32
// agg partial per block + atomic asum.
// Wave wv: logits (kw=wv&3 -> k range 16, sgrp=wv>>2 -> s half 32);
//          agg (d range 64 at wv*64, all 64 k).
// MFMA conv: D[row=4q+r][col=lane&15]; row<-1st operand, col<-2nd.
// ---------------------------------------------------------------------------
__global__ __launch_bounds__(512, 2) void kF(const float* __restrict__ x,
                                             const short* __restrict__ w16,
                                             float* __restrict__ aggp,
                                             float* __restrict__ asum)
{
    __shared__ short T[64 * TP];        // x-tile, transposed [s][d] bf16 (68.6 KB)
    __shared__ short aP[64 * AP];       // a' = softmax*inv, [k][s] bf16 (9.2 KB)
    __shared__ float pssq[32 * PP];     // per-dgroup partial ssq (8.7 KB)
    __shared__ float invL[64];
    __shared__ float wredS[2][4][66];   // cross-wave max/sum (2.1 KB)

    const int tid = threadIdx.x;
    const int wv  = tid >> 6;
    const int l   = tid & 63;
    const int lk  = l & 15;
    const int q   = l >> 4;
    const int kw  = wv & 3;             // logits k range [16*kw, 16*kw+16)
    const int sgrp = wv >> 2;           // logits s half
    const int dg  = tid >> 4;           // staging d-row group 0..31
    const int n   = blockIdx.x >> 3;
    const int bj  = blockIdx.x & 7;
    const int nst = (bj == 0) ? 4 : 3;

    const float* xb = x + (size_t)n * D_ * S_;

    f32x4 acc[4][4];                    // agg acc: [kt][ds] (64 VGPR)
#pragma unroll
    for (int a = 0; a < 4; ++a)
#pragma unroll
        for (int b = 0; b < 4; ++b) acc[a][b] = (f32x4){0.f, 0.f, 0.f, 0.f};
    float asum_loc[4] = {0.f, 0.f, 0.f, 0.f};

    for (int it = 0; it < nst; ++it) {
        const int s0 = (bj + 8 * it) * 64;
        __syncthreads();   // (1) prev iter's agg done: T/aP safe to overwrite

        // ---- stage x-tile: fp32 -> bf16, 4x4 in-register lane transpose ----
        // lane loads float4 = x[d = dg+32j][s0+4lk .. +3]; lanes {lk+16q}
        // (d consecutive over q) transpose so lane ends with s=4lk+q, d 4-run.
        float ssql[4] = {0.f, 0.f, 0.f, 0.f};
#pragma unroll
        for (int j = 0; j < 16; ++j) {
            const int d = dg + 32 * j;
            const float4 v = *(const float4*)&xb[(size_t)d * S_ + s0 + 4 * lk];
            ssql[0] += v.x * v.x;  ssql[1] += v.y * v.y;
            ssql[2] += v.z * v.z;  ssql[3] += v.w * v.w;
            unsigned p0 = pk2(v.x, v.y), p1 = pk2(v.z, v.w);
            // stage 1: exchange halves across q^2 (lane bit 5)
            unsigned mine = (l & 32) ? p0 : p1;
            unsigned oth  = (unsigned)__shfl_xor((int)mine, 32);
            unsigned a0 = (l & 32) ? oth : p0;   // sPair of d-parity 0 pairset
            unsigned a1 = (l & 32) ? p1 : oth;
            // stage 2: u16 interleave across q^1 (lane bit 4)
            unsigned r0 = (unsigned)__shfl_xor((int)a0, 16);
            unsigned r1 = (unsigned)__shfl_xor((int)a1, 16);
            unsigned o0, o1;
            if (l & 16) {
                o0 = (r0 >> 16) | (a0 & 0xffff0000u);
                o1 = (r1 >> 16) | (a1 & 0xffff0000u);
            } else {
                o0 = (a0 & 0xffffu) | (r0 << 16);
                o1 = (a1 & 0xffffu) | (r1 << 16);
            }
            // lane now holds s = 4lk+q, d = 4wv+32j .. +3  -> one b64 store
            *(u32x2*)&T[(4 * lk + q) * TP + 4 * wv + 32 * j] = (u32x2){o0, o1};
        }
        *(float4*)&pssq[dg * PP + 4 * lk] = (float4){ssql[0], ssql[1], ssql[2], ssql[3]};
        __syncthreads();   // (2) T + pssq ready

        if (tid < 64) {
            float ss = 0.f;
#pragma unroll
            for (int g = 0; g < 32; ++g) ss += pssq[g * PP + tid];
            invL[tid] = 1.0f / fmaxf(sqrtf(ss), 1e-12f);
        }

        // ---- logits GEMM: [16 k] x [32 s], K-dim d=512 ----
        f32x4 accl0 = (f32x4){0.f, 0.f, 0.f, 0.f};
        f32x4 accl1 = accl0;
        const short* wrow = w16 + (size_t)(16 * kw + lk) * D_;
        const short* tr0  = &T[(sgrp * 32 + lk) * TP];
        const short* tr1  = tr0 + 16 * TP;
#pragma unroll
        for (int kst = 0; kst < 16; ++kst) {
            short8 af = *(const short8*)&wrow[kst * 32 + q * 8];
            short8 b0 = *(const short8*)&tr0[kst * 32 + q * 8];
            short8 b1 = *(const short8*)&tr1[kst * 32 + q * 8];
            accl0 = __builtin_amdgcn_mfma_f32_16x16x32_bf16(af, b0, accl0, 0, 0, 0);
            accl1 = __builtin_amdgcn_mfma_f32_16x16x32_bf16(af, b1, accl1, 0, 0, 0);
        }
        __syncthreads();   // (3) invL ready; all logits done

        // ---- softmax over k (in-lane r -> shfl q -> LDS kw) ----
        const int sA0 = sgrp * 32 + lk;
        const float invv0 = invL[sA0];
        const float invv1 = invL[sA0 + 16];
        float lg0[4], lg1[4];
#pragma unroll
        for (int r = 0; r < 4; ++r) { lg0[r] = accl0[r] * invv0; lg1[r] = accl1[r] * invv1; }
        float m0 = fmaxf(fmaxf(lg0[0], lg0[1]), fmaxf(lg0[2], lg0[3]));
        float m1 = fmaxf(fmaxf(lg1[0], lg1[1]), fmaxf(lg1[2], lg1[3]));
        m0 = fmaxf(m0, __shfl_xor(m0, 16));  m0 = fmaxf(m0, __shfl_xor(m0, 32));
        m1 = fmaxf(m1, __shfl_xor(m1, 16));  m1 = fmaxf(m1, __shfl_xor(m1, 32));
        if (q == 0) { wredS[0][kw][sA0] = m0;  wredS[0][kw][sA0 + 16] = m1; }
        __syncthreads();   // (4)
        const float gm0 = fmaxf(fmaxf(wredS[0][0][sA0], wredS[0][1][sA0]),
                                fmaxf(wredS[0][2][sA0], wredS[0][3][sA0]));
        const float gm1 = fmaxf(fmaxf(wredS[0][0][sA0 + 16], wredS[0][1][sA0 + 16]),
                                fmaxf(wredS[0][2][sA0 + 16], wredS[0][3][sA0 + 16]));
        float e0[4], e1[4];
        float sm0 = 0.f, sm1 = 0.f;
#pragma unroll
        for (int r = 0; r < 4; ++r) {
            e0[r] = __expf(lg0[r] - gm0);  sm0 += e0[r];
            e1[r] = __expf(lg1[r] - gm1);  sm1 += e1[r];
        }
        sm0 += __shfl_xor(sm0, 16);  sm0 += __shfl_xor(sm0, 32);
        sm1 += __shfl_xor(sm1, 16);  sm1 += __shfl_xor(sm1, 32);
        if (q == 0) { wredS[1][kw][sA0] = sm0;  wredS[1][kw][sA0 + 16] = sm1; }
        __syncthreads();   // (5)
        const float rs0 = 1.0f / (wredS[1][0][sA0] + wredS[1][1][sA0]
                                + wredS[1][2][sA0] + wredS[1][3][sA0]);
        const float rs1 = 1.0f / (wredS[1][0][sA0 + 16] + wredS[1][1][sA0 + 16]
                                + wredS[1][2][sA0 + 16] + wredS[1][3][sA0 + 16]);
#pragma unroll
        for (int r = 0; r < 4; ++r) {
            const int krow = 16 * kw + 4 * q + r;
            const float pa = e0[r] * rs0;
            const float pb = e1[r] * rs1;
            aP[krow * AP + sA0]      = f2bf(pa * invv0);
            aP[krow * AP + sA0 + 16] = f2bf(pb * invv1);
            asum_loc[r] += pa + pb;
        }
        __syncthreads();   // (6) aP ready

        // ---- agg GEMM: acc[k][d] += a'[k][s] * x[d][s], K-dim s=64 ----
        const int dbase = wv * 64;
#pragma unroll
        for (int k2 = 0; k2 < 2; ++k2) {
            const int sA = k2 * 32 + q * 8;
            short8 afr[4];
#pragma unroll
            for (int kt = 0; kt < 4; ++kt)
                afr[kt] = *(const short8*)&aP[(kt * 16 + lk) * AP + sA];
            short8 bfr[4];
#pragma unroll
            for (int ds = 0; ds < 4; ++ds) {
                const float* xp = &xb[(size_t)(dbase + ds * 16 + lk) * S_ + s0 + sA];
                float4 v0 = *(const float4*)xp;         // L2 hit: just staged
                float4 v1 = *(const float4*)(xp + 4);
                short8 b;
                b[0] = f2bf(v0.x); b[1] = f2bf(v0.y); b[2] = f2bf(v0.z); b[3] = f2bf(v0.w);
                b[4] = f2bf(v1.x); b[5] = f2bf(v1.y); b[6] = f2bf(v1.z); b[7] = f2bf(v1.w);
                bfr[ds] = b;
            }
#pragma unroll
            for (int kt = 0; kt < 4; ++kt)
#pragma unroll
                for (int ds = 0; ds < 4; ++ds)
                    acc[kt][ds] = __builtin_amdgcn_mfma_f32_16x16x32_bf16(afr[kt], bfr[ds], acc[kt][ds], 0, 0, 0);
        }
    }

    // ---- write agg partial: aggp[bj][n][k][d] ----
    float* ab = aggp + ((size_t)bj * N_ + n) * K_ * D_;
#pragma unroll
    for (int kt = 0; kt < 4; ++kt)
#pragma unroll
        for (int ds = 0; ds < 4; ++ds)
#pragma unroll
            for (int r = 0; r < 4; ++r)
                ab[(size_t)(kt * 16 + 4 * q + r) * D_ + wv * 64 + ds * 16 + lk] = acc[kt][ds][r];

    // ---- asum: reduce over lk within 16-lane group, one atomic per k ----
#pragma unroll
    for (int r = 0; r < 4; ++r) {
        float v = asum_loc[r];
        v += __shfl_xor(v, 1);  v += __shfl_xor(v, 2);
        v += __shfl_xor(v, 4);  v += __shfl_xor(v, 8);
        if (lk == 0) atomicAdd(&asum[n * K_ + 16 * kw + 4 * q + r], v);
    }
}

// ---------------------------------------------------------------------------
// kC: vlad = (sum of NSP agg partials) - asum*centroid; intra-L2-norm over d;
// global norm = /sqrt(K) = /8 exactly. grid: 2048 blocks x 256 thr.
// ---------------------------------------------------------------------------
__global__ __launch_bounds__(256) void kC(const float* __restrict__ aggp,
                                          const float* __restrict__ asum,
                                          const float* __restrict__ cent,
                                          float* __restrict__ out)
{
    __shared__ float red[4];
    const int tid = threadIdx.x;
    const int nk = blockIdx.x;
    const int k = nk & 63;
    const float as = asum[nk];
    const float* cb = cent + (size_t)k * D_;

    float v0 = 0.f, v1 = 0.f;
#pragma unroll
    for (int p = 0; p < NSP; ++p) {
        const float* ag = aggp + (size_t)p * N_ * K_ * D_ + (size_t)nk * D_;
        v0 += ag[tid];
        v1 += ag[tid + 256];
    }
    v0 -= as * cb[tid];
    v1 -= as * cb[tid + 256];
    float ssq = v0 * v0 + v1 * v1;

    ssq += __shfl_xor(ssq, 32);
    ssq += __shfl_xor(ssq, 16);
    ssq += __shfl_xor(ssq, 8);
    ssq += __shfl_xor(ssq, 4);
    ssq += __shfl_xor(ssq, 2);
    ssq += __shfl_xor(ssq, 1);
    if ((tid & 63) == 0) red[tid >> 6] = ssq;
    __syncthreads();
    const float total = red[0] + red[1] + red[2] + red[3];
    const float scale = 1.0f / (fmaxf(sqrtf(total), 1e-12f) * 8.0f);

    out[(size_t)nk * D_ + tid]       = v0 * scale;
    out[(size_t)nk * D_ + tid + 256] = v1 * scale;
}

// ---------------------------------------------------------------------------
extern "C" void kernel_launch(void* const* d_in, const int* in_sizes, int n_in,
                              void* d_out, int out_size, void* d_ws, size_t ws_size,
                              hipStream_t stream)
{
    const float* x    = (const float*)d_in[0];   // [32,512,40,40]
    const float* w    = (const float*)d_in[1];   // [64,512]
    const float* cent = (const float*)d_in[2];   // [64,512]
    float* out = (float*)d_out;                  // [32, 32768]

    // ws carve (~33.6 MB), 16B-aligned throughout
    float* aggp = (float*)d_ws;                          // NSP*32*64*512 fp32
    float* asum = aggp + (size_t)NSP * N_ * K_ * D_;     // 2048 fp32
    short* w16  = (short*)(asum + N_ * K_);              // 32768 bf16

    hipMemsetAsync(asum, 0, (size_t)N_ * K_ * sizeof(float), stream);

    kW<<<32, 256, 0, stream>>>(w, w16);
    kF<<<N_ * NSP, 512, 0, stream>>>(x, w16, aggp, asum);
    kC<<<N_ * K_, 256, 0, stream>>>(aggp, asum, cent, out);
}